// Round 1
// baseline (2035.154 us; speedup 1.0000x reference)
//
#include <hip/hip_runtime.h>
#include <math.h>

// EQNetwork (tensor-field-network style) on MI355X, fp32 vector-ALU implementation.
// N=10000 nodes, K=16 neighbors, 3 gated conv layers. No fp32 MFMA on CDNA4 ->
// VALU-bound; floor ~403us at 157 TF. Design: 64 edges (4 nodes) per block,
// LDS-chunked weight staging, register-blocked GEMMs, shuffle-reduced tensor
// product contraction, per-block scatter-mean (edges of a node are contiguous).

#define NTOT 10000
#define HD   100
#define NBAS 10

__global__ void prep_kernel(const int* __restrict__ charges, float* __restrict__ f00) {
  int n = blockIdx.x * 256 + threadIdx.x;
  if (n < NTOT) f00[n] = (float)charges[n] / 94.0f - 0.5f;
}

template<int M0I, int M1I, int M0O, int NG, int M1O>
__global__ __launch_bounds__(256, 2) void layer_kernel(
    const float* __restrict__ radii, const int* __restrict__ nbr,
    const float* __restrict__ f0prev, const float* __restrict__ f1prev,
    const float* __restrict__ w1, const float* __restrict__ b1,
    const float* __restrict__ w2, const float* __restrict__ b2,
    const float* __restrict__ w3,
    float* __restrict__ f0next, float* __restrict__ f1next)
{
  constexpr int M0T = M0O + NG;
  constexpr int O   = M0T*M0I + M0T*M1I + M1O*M0I + 2*M1O*M1I;
  constexpr int OFF01  = M0T*M0I;
  constexpr int OFF10  = OFF01 + M0T*M1I;
  constexpr int OFF11A = OFF10 + M1O*M0I;
  constexpr int OFF11B = OFF11A + M1O*M1I;
  constexpr int CW  = (O >= 64) ? 64 : O;   // 64 for L2/L3, 32 for L1
  constexpr int NCH = O / CW;
  constexpr int NRJ = CW / 16;              // cols per thread (strided by 16)
  static_assert(O % CW == 0, "chunk must divide O");

  __shared__ __align__(16) float sh_h2[64*HD];        // 25600 B
  __shared__ __align__(16) char  RA[64*HD*4];         // h1 | w3q[25][CW] float4
  __shared__ __align__(16) char  RB[25*32*16];        // w1 | w2q[25][32] float4
  __shared__ float sh_s[64*M0T];
  __shared__ float sh_a10[(M1O>0)?64*M1O:1];
  __shared__ float sh_v[(M1O>0)?64*M1O*3:1];
  __shared__ float sh_u[64*3];
  __shared__ float sh_r[64];
  __shared__ int   sh_idx[64];
  __shared__ float sh_b1[HD];
  __shared__ float sh_b2[HD];

  const int tid = threadIdx.x;
  const int ct  = tid & 15;     // column-thread (maps to i-index of TP groups)
  const int et  = tid >> 4;     // edge-thread
  const int eg0 = blockIdx.x * 64;

  // ---------- phase 0: geometry, staging, accumulator zero ----------
  if (tid < 64) {
    float x = radii[(eg0+tid)*3+0];
    float y = radii[(eg0+tid)*3+1];
    float z = radii[(eg0+tid)*3+2];
    float rr = sqrtf(x*x + y*y + z*z);
    float inv = 1.0f / (rr + 1e-8f);
    sh_u[tid*3+0] = x*inv;
    sh_u[tid*3+1] = y*inv;
    sh_u[tid*3+2] = z*inv;
    sh_r[tid] = rr;
    sh_idx[tid] = nbr[eg0 + tid];
  }
  {
    float* w1s = (float*)RB;
    for (int p = tid; p < NBAS*HD; p += 256) w1s[p] = w1[p];
  }
  for (int p = tid; p < HD; p += 256) { sh_b1[p] = b1[p]; sh_b2[p] = b2[p]; }
  for (int p = tid; p < 64*M0T; p += 256) sh_s[p] = 0.0f;
  if (M1O > 0) {
    for (int p = tid; p < 64*M1O; p += 256)   sh_a10[p] = 0.0f;
    for (int p = tid; p < 64*M1O*3; p += 256) sh_v[p] = 0.0f;
  }
  __syncthreads();

  // ---------- h1 = relu(basis @ w1 + b1) ----------
  {
    float* h1 = (float*)RA;
    const float* w1s = (const float*)RB;
    const int e  = tid & 63;
    const int jg = tid >> 6;
    const float rr = sh_r[e];
    float bas[NBAS];
    constexpr float STEP = 5.0f/9.0f;
    #pragma unroll
    for (int nb = 0; nb < NBAS; ++nb) {
      float d = (rr - (float)nb*STEP) / STEP;
      float c = cosf(1.5707964f * d);
      bas[nb] = (fabsf(d) < 1.0f) ? c*c : 0.0f;
    }
    const int j0 = jg*25;
    for (int j = j0; j < j0+25; ++j) {
      float acc = sh_b1[j];
      #pragma unroll
      for (int nb = 0; nb < NBAS; ++nb) acc = fmaf(bas[nb], w1s[nb*HD + j], acc);
      h1[e*HD + j] = fmaxf(acc, 0.0f);
    }
  }

  // ---------- phase 1: h2 = relu(h1 @ w2 + b2), 32-col chunks ----------
  {
    float4 (*w2q)[32] = (float4(*)[32])RB;
    const float* h1 = (const float*)RA;
    for (int c1 = 0; c1 < HD; c1 += 32) {
      const int cw = (HD - c1 < 32) ? (HD - c1) : 32;   // 32,32,32,4
      __syncthreads();
      for (int p = tid; p < cw*25; p += 256) {
        int col = p % cw, kk = p / cw;
        float4 vv;
        vv.x = w2[(4*kk+0)*HD + c1 + col];
        vv.y = w2[(4*kk+1)*HD + c1 + col];
        vv.z = w2[(4*kk+2)*HD + c1 + col];
        vv.w = w2[(4*kk+3)*HD + c1 + col];
        w2q[kk][col] = vv;
      }
      __syncthreads();
      const int nj = (ct < cw) ? ((ct + 16 < cw) ? 2 : 1) : 0;
      if (nj > 0) {
        float acc[4][2];
        #pragma unroll
        for (int q = 0; q < 4; ++q) { acc[q][0] = 0.0f; acc[q][1] = 0.0f; }
        for (int kk = 0; kk < 25; ++kk) {
          float4 bv[2];
          for (int j = 0; j < nj; ++j) bv[j] = w2q[kk][ct + 16*j];
          #pragma unroll
          for (int q = 0; q < 4; ++q) {
            float4 a = *(const float4*)&h1[(et + 16*q)*HD + 4*kk];
            for (int j = 0; j < nj; ++j)
              acc[q][j] = fmaf(a.x, bv[j].x, fmaf(a.y, bv[j].y,
                          fmaf(a.z, bv[j].z, fmaf(a.w, bv[j].w, acc[q][j]))));
          }
        }
        #pragma unroll
        for (int q = 0; q < 4; ++q)
          for (int j = 0; j < nj; ++j) {
            int jgl = c1 + ct + 16*j;
            sh_h2[(et+16*q)*HD + jgl] = fmaxf(acc[q][j] + sh_b2[jgl], 0.0f);
          }
      }
    }
  }

  // ---------- phase 2: W = h2 @ w3 (chunked) fused with TP contraction ----------
  {
    float4 (*w3q)[CW] = (float4(*)[CW])RA;
    for (int ch = 0; ch < NCH; ++ch) {
      const int c0 = ch * CW;
      __syncthreads();
      for (int p = tid; p < CW*25; p += 256) {
        int col = p % CW, kk = p / CW;
        float4 vv;
        vv.x = w3[(4*kk+0)*O + c0 + col];
        vv.y = w3[(4*kk+1)*O + c0 + col];
        vv.z = w3[(4*kk+2)*O + c0 + col];
        vv.w = w3[(4*kk+3)*O + c0 + col];
        w3q[kk][col] = vv;
      }
      __syncthreads();

      // --- prefetch contraction operands (hidden under the k-loop) ---
      // mode: 0 = L1 per-column (M0I==1), 1 = g0 path redw16 (W00/W10),
      //       2 = W01 (p1=g1.u, redw8), 3 = W11a/b (vector, redw8)
      int mode;
      const float* tgt = sh_s; int tstride = M0T; int obase = 0;
      if (M0I == 1) {
        mode = 0;
      } else if (c0 < OFF01) {
        mode = 1; tgt = sh_s; tstride = M0T; obase = c0 >> 4;
      } else if (c0 < OFF10) {
        mode = 2; obase = ((c0 - OFF01) >> 3) + (ct >> 3);
      } else if (M1O > 0 && c0 < OFF11A) {
        mode = 1; tgt = sh_a10; tstride = M1O; obase = (c0 - OFF10) >> 4;
      } else {
        mode = 3;
      }
      float pv[4], pvy[4], pvz[4];
      if (mode == 0) {
        #pragma unroll
        for (int q = 0; q < 4; ++q) pv[q] = 0.5f * f0prev[sh_idx[et + 16*q]];
      } else if (mode == 1) {
        #pragma unroll
        for (int q = 0; q < 4; ++q) pv[q] = 0.5f * f0prev[sh_idx[et + 16*q]*M0I + ct];
      } else if (mode == 2) {
        const int i = ct & 7;
        #pragma unroll
        for (int q = 0; q < 4; ++q) {
          int e = et + 16*q;
          int base = (sh_idx[e]*M1I + i)*3;
          float p1 = f1prev[base+0]*sh_u[e*3+0] + f1prev[base+1]*sh_u[e*3+1]
                   + f1prev[base+2]*sh_u[e*3+2];
          pv[q] = 0.5f * p1;
        }
      } else {  // mode 3
        const bool is_b = (c0 >= OFF11B);
        const int i = ct & 7;
        #pragma unroll
        for (int q = 0; q < 4; ++q) {
          int e = et + 16*q;
          int base = (sh_idx[e]*M1I + i)*3;
          float ax = f1prev[base+0], ay = f1prev[base+1], az = f1prev[base+2];
          if (is_b) {
            float ux = sh_u[e*3+0], uy = sh_u[e*3+1], uz = sh_u[e*3+2];
            pv[q]  = 0.5f*(ay*uz - az*uy);
            pvy[q] = 0.5f*(az*ux - ax*uz);
            pvz[q] = 0.5f*(ax*uy - ay*ux);
          } else {
            pv[q] = 0.5f*ax; pvy[q] = 0.5f*ay; pvz[q] = 0.5f*az;
          }
        }
      }

      // --- k-loop: W[e, col] for 4 edges x NRJ strided cols ---
      float acc[4][NRJ];
      #pragma unroll
      for (int q = 0; q < 4; ++q)
        #pragma unroll
        for (int j = 0; j < NRJ; ++j) acc[q][j] = 0.0f;
      for (int kk = 0; kk < 25; ++kk) {
        float4 bv[NRJ];
        #pragma unroll
        for (int j = 0; j < NRJ; ++j) bv[j] = w3q[kk][ct + 16*j];
        #pragma unroll
        for (int q = 0; q < 4; ++q) {
          float4 a = *(const float4*)&sh_h2[(et + 16*q)*HD + 4*kk];
          #pragma unroll
          for (int j = 0; j < NRJ; ++j)
            acc[q][j] = fmaf(a.x, bv[j].x, fmaf(a.y, bv[j].y,
                        fmaf(a.z, bv[j].z, fmaf(a.w, bv[j].w, acc[q][j]))));
        }
      }

      // --- contraction ---
      if (mode == 0) {
        #pragma unroll
        for (int q = 0; q < 4; ++q) {
          int e = et + 16*q;
          #pragma unroll
          for (int j = 0; j < NRJ; ++j) {
            int col = c0 + ct + 16*j;
            float val = acc[q][j] * pv[q];
            if (col < OFF01) sh_s[e*M0T + col] += val;
            else if (M1O > 0) sh_a10[e*M1O + (col - OFF01)] += val;
          }
        }
      } else if (mode == 1) {
        #pragma unroll
        for (int q = 0; q < 4; ++q) {
          int e = et + 16*q;
          float part[NRJ];
          #pragma unroll
          for (int j = 0; j < NRJ; ++j) part[j] = acc[q][j] * pv[q];
          #pragma unroll
          for (int off = 1; off < 16; off <<= 1)
            #pragma unroll
            for (int j = 0; j < NRJ; ++j) part[j] += __shfl_xor(part[j], off);
          if (ct == 0) {
            float* t = const_cast<float*>(tgt);
            #pragma unroll
            for (int j = 0; j < NRJ; ++j) t[e*tstride + obase + j] += part[j];
          }
        }
      } else if (mode == 2) {
        #pragma unroll
        for (int q = 0; q < 4; ++q) {
          int e = et + 16*q;
          float part[NRJ];
          #pragma unroll
          for (int j = 0; j < NRJ; ++j) part[j] = acc[q][j] * pv[q];
          #pragma unroll
          for (int off = 1; off < 8; off <<= 1)
            #pragma unroll
            for (int j = 0; j < NRJ; ++j) part[j] += __shfl_xor(part[j], off);
          if ((ct & 7) == 0) {
            #pragma unroll
            for (int j = 0; j < NRJ; ++j) sh_s[e*M0T + obase + 2*j] += part[j];
          }
        }
      } else if (M1O > 0) {  // mode 3
        const bool is_b = (c0 >= OFF11B);
        const int ob = ((c0 - (is_b ? OFF11B : OFF11A)) >> 3) + (ct >> 3);
        #pragma unroll
        for (int q = 0; q < 4; ++q) {
          int e = et + 16*q;
          float px[NRJ], py[NRJ], pz[NRJ];
          #pragma unroll
          for (int j = 0; j < NRJ; ++j) {
            px[j] = acc[q][j] * pv[q];
            py[j] = acc[q][j] * pvy[q];
            pz[j] = acc[q][j] * pvz[q];
          }
          #pragma unroll
          for (int off = 1; off < 8; off <<= 1)
            #pragma unroll
            for (int j = 0; j < NRJ; ++j) {
              px[j] += __shfl_xor(px[j], off);
              py[j] += __shfl_xor(py[j], off);
              pz[j] += __shfl_xor(pz[j], off);
            }
          if ((ct & 7) == 0) {
            #pragma unroll
            for (int j = 0; j < NRJ; ++j) {
              int oo = ob + 2*j;
              sh_v[(e*M1O+oo)*3+0] += px[j];
              sh_v[(e*M1O+oo)*3+1] += py[j];
              sh_v[(e*M1O+oo)*3+2] += pz[j];
            }
          }
        }
      }
    }
  }
  __syncthreads();

  // ---------- finalize: mean over K=16, relu / sigmoid gating, write ----------
  if (tid < 4*M0T) {
    const int nl = tid / M0T;
    const int o  = tid - nl*M0T;
    float ssum = 0.0f;
    for (int k = 0; k < 16; ++k) ssum += sh_s[(nl*16+k)*M0T + o];
    const float sm = ssum * 0.0625f;
    const int n = blockIdx.x*4 + nl;
    if (o < M0O) {
      f0next[n*M0O + o] = fmaxf(sm, 0.0f);
    } else if (M1O > 0) {
      const int og = o - M0O;
      const float gate = 1.0f / (1.0f + expf(-sm));
      float vx = 0.0f, vy = 0.0f, vz = 0.0f;
      for (int k = 0; k < 16; ++k) {
        int e = nl*16 + k;
        float a = sh_a10[e*M1O + og];
        vx += fmaf(a, sh_u[e*3+0], sh_v[(e*M1O+og)*3+0]);
        vy += fmaf(a, sh_u[e*3+1], sh_v[(e*M1O+og)*3+1]);
        vz += fmaf(a, sh_u[e*3+2], sh_v[(e*M1O+og)*3+2]);
      }
      const float sc = gate * 0.0625f;
      f1next[(n*M1O+og)*3+0] = vx * sc;
      f1next[(n*M1O+og)*3+1] = vy * sc;
      f1next[(n*M1O+og)*3+2] = vz * sc;
    }
  }
}

__global__ void reduce_kernel(const float* __restrict__ f0c, float* __restrict__ out) {
  __shared__ float red[256];
  const int o = blockIdx.x;  // 0..31
  float s = 0.0f;
  for (int n = threadIdx.x; n < NTOT; n += 256) s += f0c[n*32 + o];
  red[threadIdx.x] = s;
  __syncthreads();
  for (int w = 128; w > 0; w >>= 1) {
    if (threadIdx.x < w) red[threadIdx.x] += red[threadIdx.x + w];
    __syncthreads();
  }
  if (threadIdx.x == 0) out[o] = red[0] / (float)NTOT;
}

extern "C" void kernel_launch(void* const* d_in, const int* in_sizes, int n_in,
                              void* d_out, int out_size, void* d_ws, size_t ws_size,
                              hipStream_t stream) {
  const float* radii   = (const float*)d_in[0];
  const int*   nbr     = (const int*)d_in[1];
  const int*   charges = (const int*)d_in[2];
  const float* l1w1 = (const float*)d_in[3];
  const float* l1b1 = (const float*)d_in[4];
  const float* l1w2 = (const float*)d_in[5];
  const float* l1b2 = (const float*)d_in[6];
  const float* l1w3 = (const float*)d_in[7];
  const float* l2w1 = (const float*)d_in[8];
  const float* l2b1 = (const float*)d_in[9];
  const float* l2w2 = (const float*)d_in[10];
  const float* l2b2 = (const float*)d_in[11];
  const float* l2w3 = (const float*)d_in[12];
  const float* l3w1 = (const float*)d_in[13];
  const float* l3b1 = (const float*)d_in[14];
  const float* l3w2 = (const float*)d_in[15];
  const float* l3b2 = (const float*)d_in[16];
  const float* l3w3 = (const float*)d_in[17];

  float* ws  = (float*)d_ws;
  float* f00 = ws;                 // [N]        10000
  float* f0a = f00 + NTOT;         // [N][16]   160000
  float* f1a = f0a + NTOT*16;      // [N][8][3] 240000
  float* f0b = f1a + NTOT*24;      // [N][16]   160000
  float* f1b = f0b + NTOT*16;      // [N][8][3] 240000
  float* f0c = f1b + NTOT*24;      // [N][32]   320000
  // total 1,130,000 floats = 4.52 MB of d_ws

  prep_kernel<<<(NTOT + 255)/256, 256, 0, stream>>>(charges, f00);

  layer_kernel<1,0,16,8,8><<<NTOT/4, 256, 0, stream>>>(
      radii, nbr, f00, nullptr, l1w1, l1b1, l1w2, l1b2, l1w3, f0a, f1a);

  layer_kernel<16,8,16,8,8><<<NTOT/4, 256, 0, stream>>>(
      radii, nbr, f0a, f1a, l2w1, l2b1, l2w2, l2b2, l2w3, f0b, f1b);

  layer_kernel<16,8,32,0,0><<<NTOT/4, 256, 0, stream>>>(
      radii, nbr, f0b, f1b, l3w1, l3b1, l3w2, l3b2, l3w3, f0c, nullptr);

  reduce_kernel<<<32, 256, 0, stream>>>(f0c, (float*)d_out);
}

// Round 2
// 722.776 us; speedup vs baseline: 2.8157x; 2.8157x over previous
//
#include <hip/hip_runtime.h>
#include <math.h>

// EQNetwork on MI355X. R2: move the radial-MLP GEMMs (97% of FLOPs) onto bf16
// MFMA (16x16x32). Weights are split hi/lo bf16 (folded into K: K=256 where
// rows 0..127=hi, 128..255=lo reuse the same A tile) to kill systematic
// rounding error; activations are single bf16 (random error averages out in
// the final mean over 10000 nodes). The verified fp32 contraction/scatter
// logic from R1 is kept unchanged, fed from an LDS W-tile written in MFMA
// C-layout (col=lane&15, row=quad*4+reg).

#define NTOT  10000
#define EDGES 160000
#define HD    100
#define NBAS  10

typedef __attribute__((ext_vector_type(8))) short short8;
typedef __attribute__((ext_vector_type(4))) float float4v;

__device__ inline unsigned short f2bf(float x) {
  unsigned u = __builtin_bit_cast(unsigned, x);
  u += 0x7fffu + ((u >> 16) & 1u);          // RNE
  return (unsigned short)(u >> 16);
}
__device__ inline float bf2f(unsigned short b) {
  unsigned u = ((unsigned)b) << 16;
  return __builtin_bit_cast(float, u);
}

// LDS fragment read for MFMA 16x16x32 bf16. Tiles are stored as rows of S
// 16B-slots with XOR swizzle: physical slot p = kb ^ (row & 15)  -> <=2-way
// bank aliasing (free) for both staging writes and fragment reads.
__device__ inline short8 fragld(const unsigned short* lds, int rbase, int S, int kb, int lane) {
  int r = rbase + (lane & 15);
  int p = kb ^ (r & 15);
  return *(const short8*)(lds + (r * S + p) * 8);
}

// ---------------- prep kernels ----------------

__global__ void prep_misc(const int* __restrict__ charges,
                          const float* __restrict__ b21, const float* __restrict__ b22,
                          const float* __restrict__ b23,
                          float* __restrict__ f00, float* __restrict__ b2pad) {
  int g = blockIdx.x * 256 + threadIdx.x;
  if (g < NTOT) f00[g] = (float)charges[g] / 94.0f - 0.5f;
  int h = g - NTOT;
  if (h >= 0 && h < 384) {
    int l = h >> 7, j = h & 127;
    const float* b = (l == 0) ? b21 : (l == 1) ? b22 : b23;
    b2pad[h] = (j < HD) ? b[j] : 0.f;
  }
}

// Split weight [Ks x Ns] (row-major, k-major) into bt[Nrows][256] bf16 where
// bt[n][k'] = hi(w[k'][n]) for k'<128, lo(w[k'-128][n]) for k'>=128 (zeros pad).
__global__ void prep_bt(const float* __restrict__ w, int Ks, int Ns, int Nrows,
                        unsigned short* __restrict__ bt) {
  int total = Nrows * 256;
  for (int g = blockIdx.x * 256 + threadIdx.x; g < total; g += gridDim.x * 256) {
    int n = g >> 8, kp = g & 255;
    int k = kp & 127;
    float v = (k < Ks && n < Ns) ? w[k * Ns + n] : 0.f;
    unsigned short hi = f2bf(v);
    bt[g] = (kp < 128) ? hi : f2bf(v - bf2f(hi));
  }
}

// ---------------- K1: basis + GEMM1 (fp32) -> h1 bf16 [64 x 128] per block ----------------

__global__ __launch_bounds__(256) void k1_kernel(const float* __restrict__ radii,
    const float* __restrict__ w1, const float* __restrict__ b1,
    unsigned short* __restrict__ h1out, int e0)
{
  __shared__ float w1s[NBAS * HD];
  __shared__ float b1s[HD];
  __shared__ __align__(16) unsigned short ot[64 * 128];
  const int tid = threadIdx.x;
  const int ebg = e0 + blockIdx.x * 64;
  for (int p = tid; p < NBAS * HD; p += 256) w1s[p] = w1[p];
  for (int p = tid; p < HD; p += 256) b1s[p] = b1[p];
  {
    short8 z = {0, 0, 0, 0, 0, 0, 0, 0};
    #pragma unroll
    for (int i = 0; i < 4; ++i) ((short8*)ot)[tid + 256 * i] = z;
  }
  __syncthreads();
  const int e = tid & 63, jg = tid >> 6;
  float x = radii[(size_t)(ebg + e) * 3 + 0];
  float y = radii[(size_t)(ebg + e) * 3 + 1];
  float z = radii[(size_t)(ebg + e) * 3 + 2];
  float rr = sqrtf(x * x + y * y + z * z);
  float bas[NBAS];
  constexpr float STEP = 5.0f / 9.0f;
  #pragma unroll
  for (int nb = 0; nb < NBAS; ++nb) {
    float d = (rr - (float)nb * STEP) / STEP;
    float c = cosf(1.5707964f * d);
    bas[nb] = (fabsf(d) < 1.0f) ? c * c : 0.0f;
  }
  int jo = e; while (jo >= 25) jo -= 25;     // rotate start col to avoid LDS bank pileup
  for (int i = 0; i < 25; ++i) {
    int j = jg * 25 + jo;
    float acc = b1s[j];
    #pragma unroll
    for (int nb = 0; nb < NBAS; ++nb) acc = fmaf(bas[nb], w1s[nb * HD + j], acc);
    ot[e * 128 + j] = f2bf(fmaxf(acc, 0.f));
    ++jo; if (jo == 25) jo = 0;
  }
  __syncthreads();
  short8* dst = (short8*)(h1out + (size_t)blockIdx.x * 8192);
  #pragma unroll
  for (int i = 0; i < 4; ++i) dst[tid + 256 * i] = ((const short8*)ot)[tid + 256 * i];
}

// ---------------- K2: h2 = relu(h1 @ w2split + b2), MFMA, 64 edges x 128 cols ----------------

__global__ __launch_bounds__(256) void k2_kernel(const unsigned short* __restrict__ h1,
    const unsigned short* __restrict__ bt2, const float* __restrict__ b2p,
    unsigned short* __restrict__ h2out)
{
  __shared__ __align__(16) unsigned short lds_A[64 * 128];     // 16 KB, reused as out tile
  __shared__ __align__(16) unsigned short lds_B[128 * 256];    // 64 KB
  __shared__ float b2s[128];
  const int tid = threadIdx.x;
  const int lane = tid & 63, w = tid >> 6, quad = lane >> 4;
  const short8* gA = (const short8*)(h1 + (size_t)blockIdx.x * 8192);
  #pragma unroll
  for (int i = 0; i < 4; ++i) {
    int g = tid + 256 * i; int row = g >> 4, kb = g & 15;
    ((short8*)lds_A)[row * 16 + (kb ^ (row & 15))] = gA[g];
  }
  const short8* gB = (const short8*)bt2;
  #pragma unroll
  for (int i = 0; i < 16; ++i) {
    int g = tid + 256 * i; int row = g >> 5, kb = g & 31;
    ((short8*)lds_B)[row * 32 + (kb ^ (row & 15))] = gB[g];
  }
  if (tid < 128) b2s[tid] = b2p[tid];
  __syncthreads();
  float4v z4 = {0.f, 0.f, 0.f, 0.f};
  float4v acc[4][2];
  #pragma unroll
  for (int a = 0; a < 4; ++a) { acc[a][0] = z4; acc[a][1] = z4; }
  for (int ks = 0; ks < 8; ++ks) {
    short8 bf0 = fragld(lds_B, (2 * w) * 16, 32, ks * 4 + quad, lane);
    short8 bf1 = fragld(lds_B, (2 * w + 1) * 16, 32, ks * 4 + quad, lane);
    #pragma unroll
    for (int eb = 0; eb < 4; ++eb) {
      short8 af = fragld(lds_A, eb * 16, 16, (ks & 3) * 4 + quad, lane);
      acc[eb][0] = __builtin_amdgcn_mfma_f32_16x16x32_bf16(af, bf0, acc[eb][0], 0, 0, 0);
      acc[eb][1] = __builtin_amdgcn_mfma_f32_16x16x32_bf16(af, bf1, acc[eb][1], 0, 0, 0);
    }
  }
  __syncthreads();   // done reading lds_A; reuse as output tile
  #pragma unroll
  for (int eb = 0; eb < 4; ++eb)
    #pragma unroll
    for (int j = 0; j < 2; ++j) {
      int n = (2 * w + j) * 16 + (lane & 15);
      #pragma unroll
      for (int r = 0; r < 4; ++r) {
        int m = eb * 16 + quad * 4 + r;
        lds_A[m * 128 + n] = f2bf(fmaxf(acc[eb][j][r] + b2s[n], 0.f));
      }
    }
  __syncthreads();
  short8* dst = (short8*)(h2out + (size_t)blockIdx.x * 8192);
  #pragma unroll
  for (int i = 0; i < 4; ++i) dst[tid + 256 * i] = ((const short8*)lds_A)[tid + 256 * i];
}

// ---------------- K3: W = h2 @ w3split (MFMA, chunked) + fused TP contraction ----------------

template<int M0I, int M1I, int M0O, int NG, int M1O>
__global__ __launch_bounds__(256, 2) void k3_kernel(
    const float* __restrict__ radii, const int* __restrict__ nbr,
    const float* __restrict__ f0prev, const float* __restrict__ f1prev,
    const unsigned short* __restrict__ h2, const unsigned short* __restrict__ bt3,
    float* __restrict__ f0next, float* __restrict__ f1next, int e0)
{
  constexpr int M0T = M0O + NG;
  constexpr int O   = M0T * M0I + M0T * M1I + M1O * M0I + 2 * M1O * M1I;
  constexpr int OFF01  = M0T * M0I;
  constexpr int OFF10  = OFF01 + M0T * M1I;
  constexpr int OFF11A = OFF10 + M1O * M0I;
  constexpr int OFF11B = OFF11A + M1O * M1I;
  constexpr int CW   = (O >= 64) ? 64 : 32;
  constexpr int NCH  = O / CW;
  constexpr int NRJ  = CW / 16;
  constexpr int WSTR = CW + 1;                 // stride 65/33 == 1 mod 32
  constexpr int NEB  = (CW == 64) ? 2 : 1;
  constexpr int NNB  = 2;
  static_assert(O % CW == 0, "chunk must divide O");

  __shared__ __align__(16) unsigned short lds_A[64 * 128];   // h2 tile, 16 KB
  __shared__ __align__(16) unsigned short lds_B[CW * 256];   // w3split chunk
  __shared__ float lds_W[64 * WSTR];
  __shared__ float sh_s[64 * M0T];
  __shared__ float sh_a10[(M1O > 0) ? 64 * M1O : 1];
  __shared__ float sh_v[(M1O > 0) ? 64 * M1O * 3 : 1];
  __shared__ float sh_u[64 * 3];
  __shared__ int   sh_idx[64];

  const int tid = threadIdx.x;
  const int lane = tid & 63, w = tid >> 6, quad = lane >> 4;
  const int ct = tid & 15, et = tid >> 4;
  const int eg0 = e0 + blockIdx.x * 64;

  if (tid < 64) {
    float x = radii[(size_t)(eg0 + tid) * 3 + 0];
    float y = radii[(size_t)(eg0 + tid) * 3 + 1];
    float z = radii[(size_t)(eg0 + tid) * 3 + 2];
    float rr = sqrtf(x * x + y * y + z * z);
    float inv = 1.0f / (rr + 1e-8f);
    sh_u[tid * 3 + 0] = x * inv;
    sh_u[tid * 3 + 1] = y * inv;
    sh_u[tid * 3 + 2] = z * inv;
    sh_idx[tid] = nbr[eg0 + tid];
  }
  for (int p = tid; p < 64 * M0T; p += 256) sh_s[p] = 0.f;
  if (M1O > 0) {
    for (int p = tid; p < 64 * M1O; p += 256)     sh_a10[p] = 0.f;
    for (int p = tid; p < 64 * M1O * 3; p += 256) sh_v[p] = 0.f;
  }
  {
    const short8* gA = (const short8*)(h2 + (size_t)blockIdx.x * 8192);
    #pragma unroll
    for (int i = 0; i < 4; ++i) {
      int g = tid + 256 * i; int row = g >> 4, kb = g & 15;
      ((short8*)lds_A)[row * 16 + (kb ^ (row & 15))] = gA[g];
    }
  }
  __syncthreads();

  const int eb0 = (CW == 64) ? (w & 1) * 2 : w;
  const int nb0 = (CW == 64) ? (w >> 1) * 2 : 0;

  for (int ch = 0; ch < NCH; ++ch) {
    const int c0 = ch * CW;
    // ---- stage B chunk (linear global read, swizzled LDS write) ----
    {
      const short8* gB = (const short8*)(bt3 + (size_t)c0 * 256);
      #pragma unroll
      for (int i = 0; i < (CW * 32) / 256; ++i) {
        int g = tid + 256 * i; int row = g >> 5, kb = g & 31;
        ((short8*)lds_B)[row * 32 + (kb ^ (row & 15))] = gB[g];
      }
    }
    __syncthreads();
    // ---- MFMA: W-tile [64 e x CW cols], K=256 (hi|lo), A k = k' mod 128 ----
    {
      float4v z4 = {0.f, 0.f, 0.f, 0.f};
      float4v acc[NEB][NNB];
      #pragma unroll
      for (int a = 0; a < NEB; ++a)
        #pragma unroll
        for (int b = 0; b < NNB; ++b) acc[a][b] = z4;
      for (int ks = 0; ks < 8; ++ks) {
        short8 bf[NNB];
        #pragma unroll
        for (int b = 0; b < NNB; ++b) bf[b] = fragld(lds_B, (nb0 + b) * 16, 32, ks * 4 + quad, lane);
        #pragma unroll
        for (int a = 0; a < NEB; ++a) {
          short8 af = fragld(lds_A, (eb0 + a) * 16, 16, (ks & 3) * 4 + quad, lane);
          #pragma unroll
          for (int b = 0; b < NNB; ++b)
            acc[a][b] = __builtin_amdgcn_mfma_f32_16x16x32_bf16(af, bf[b], acc[a][b], 0, 0, 0);
        }
      }
      #pragma unroll
      for (int a = 0; a < NEB; ++a)
        #pragma unroll
        for (int b = 0; b < NNB; ++b) {
          int col = (nb0 + b) * 16 + (lane & 15);
          #pragma unroll
          for (int r = 0; r < 4; ++r) {
            int e = (eb0 + a) * 16 + quad * 4 + r;
            lds_W[e * WSTR + col] = acc[a][b][r];
          }
        }
    }
    __syncthreads();
    // ---- contraction (R1-verified logic; acc values read from lds_W) ----
    {
      int mode;
      float* tgt = sh_s; int tstride = M0T; int obase = 0;
      if (M0I == 1) {
        mode = 0;
      } else if (c0 < OFF01) {
        mode = 1; tgt = sh_s; tstride = M0T; obase = c0 >> 4;
      } else if (c0 < OFF10) {
        mode = 2; obase = ((c0 - OFF01) >> 3) + (ct >> 3);
      } else if (M1O > 0 && c0 < OFF11A) {
        mode = 1; tgt = sh_a10; tstride = M1O; obase = (c0 - OFF10) >> 4;
      } else {
        mode = 3;
      }
      float pv[4], pvy[4], pvz[4];
      if (mode == 0) {
        #pragma unroll
        for (int q = 0; q < 4; ++q) pv[q] = 0.5f * f0prev[sh_idx[et + 16 * q]];
      } else if (mode == 1) {
        #pragma unroll
        for (int q = 0; q < 4; ++q) pv[q] = 0.5f * f0prev[sh_idx[et + 16 * q] * M0I + ct];
      } else if (mode == 2) {
        const int i = ct & 7;
        #pragma unroll
        for (int q = 0; q < 4; ++q) {
          int e = et + 16 * q;
          int base = (sh_idx[e] * M1I + i) * 3;
          float p1 = f1prev[base + 0] * sh_u[e * 3 + 0] + f1prev[base + 1] * sh_u[e * 3 + 1]
                   + f1prev[base + 2] * sh_u[e * 3 + 2];
          pv[q] = 0.5f * p1;
        }
      } else {
        const bool is_b = (c0 >= OFF11B);
        const int i = ct & 7;
        #pragma unroll
        for (int q = 0; q < 4; ++q) {
          int e = et + 16 * q;
          int base = (sh_idx[e] * M1I + i) * 3;
          float ax = f1prev[base + 0], ay = f1prev[base + 1], az = f1prev[base + 2];
          if (is_b) {
            float ux = sh_u[e * 3 + 0], uy = sh_u[e * 3 + 1], uz = sh_u[e * 3 + 2];
            pv[q]  = 0.5f * (ay * uz - az * uy);
            pvy[q] = 0.5f * (az * ux - ax * uz);
            pvz[q] = 0.5f * (ax * uy - ay * ux);
          } else {
            pv[q] = 0.5f * ax; pvy[q] = 0.5f * ay; pvz[q] = 0.5f * az;
          }
        }
      }

      float accv[4][NRJ];
      #pragma unroll
      for (int q = 0; q < 4; ++q)
        #pragma unroll
        for (int j = 0; j < NRJ; ++j) accv[q][j] = lds_W[(et + 16 * q) * WSTR + ct + 16 * j];

      if (mode == 0) {
        #pragma unroll
        for (int q = 0; q < 4; ++q) {
          int e = et + 16 * q;
          #pragma unroll
          for (int j = 0; j < NRJ; ++j) {
            int col = c0 + ct + 16 * j;
            float val = accv[q][j] * pv[q];
            if (col < OFF01) sh_s[e * M0T + col] += val;
            else if (M1O > 0) sh_a10[e * M1O + (col - OFF01)] += val;
          }
        }
      } else if (mode == 1) {
        #pragma unroll
        for (int q = 0; q < 4; ++q) {
          int e = et + 16 * q;
          float part[NRJ];
          #pragma unroll
          for (int j = 0; j < NRJ; ++j) part[j] = accv[q][j] * pv[q];
          #pragma unroll
          for (int off = 1; off < 16; off <<= 1)
            #pragma unroll
            for (int j = 0; j < NRJ; ++j) part[j] += __shfl_xor(part[j], off);
          if (ct == 0) {
            #pragma unroll
            for (int j = 0; j < NRJ; ++j) tgt[e * tstride + obase + j] += part[j];
          }
        }
      } else if (mode == 2) {
        #pragma unroll
        for (int q = 0; q < 4; ++q) {
          int e = et + 16 * q;
          float part[NRJ];
          #pragma unroll
          for (int j = 0; j < NRJ; ++j) part[j] = accv[q][j] * pv[q];
          #pragma unroll
          for (int off = 1; off < 8; off <<= 1)
            #pragma unroll
            for (int j = 0; j < NRJ; ++j) part[j] += __shfl_xor(part[j], off);
          if ((ct & 7) == 0) {
            #pragma unroll
            for (int j = 0; j < NRJ; ++j) sh_s[e * M0T + obase + 2 * j] += part[j];
          }
        }
      } else if (M1O > 0) {
        const bool is_b = (c0 >= OFF11B);
        const int ob = ((c0 - (is_b ? OFF11B : OFF11A)) >> 3) + (ct >> 3);
        #pragma unroll
        for (int q = 0; q < 4; ++q) {
          int e = et + 16 * q;
          float px[NRJ], py[NRJ], pz[NRJ];
          #pragma unroll
          for (int j = 0; j < NRJ; ++j) {
            px[j] = accv[q][j] * pv[q];
            py[j] = accv[q][j] * pvy[q];
            pz[j] = accv[q][j] * pvz[q];
          }
          #pragma unroll
          for (int off = 1; off < 8; off <<= 1)
            #pragma unroll
            for (int j = 0; j < NRJ; ++j) {
              px[j] += __shfl_xor(px[j], off);
              py[j] += __shfl_xor(py[j], off);
              pz[j] += __shfl_xor(pz[j], off);
            }
          if ((ct & 7) == 0) {
            #pragma unroll
            for (int j = 0; j < NRJ; ++j) {
              int oo = ob + 2 * j;
              sh_v[(e * M1O + oo) * 3 + 0] += px[j];
              sh_v[(e * M1O + oo) * 3 + 1] += py[j];
              sh_v[(e * M1O + oo) * 3 + 2] += pz[j];
            }
          }
        }
      }
    }
  }
  __syncthreads();

  // ---- finalize: mean over K=16, relu / sigmoid gating, write ----
  if (tid < 4 * M0T) {
    const int nl = tid / M0T;
    const int o  = tid - nl * M0T;
    float ssum = 0.0f;
    for (int k = 0; k < 16; ++k) ssum += sh_s[(nl * 16 + k) * M0T + o];
    const float sm = ssum * 0.0625f;
    const int n = (eg0 >> 4) + nl;
    if (o < M0O) {
      f0next[n * M0O + o] = fmaxf(sm, 0.0f);
    } else if (M1O > 0) {
      const int og = o - M0O;
      const float gate = 1.0f / (1.0f + expf(-sm));
      float vx = 0.f, vy = 0.f, vz = 0.f;
      for (int k = 0; k < 16; ++k) {
        int e = nl * 16 + k;
        float a = sh_a10[e * M1O + og];
        vx += fmaf(a, sh_u[e * 3 + 0], sh_v[(e * M1O + og) * 3 + 0]);
        vy += fmaf(a, sh_u[e * 3 + 1], sh_v[(e * M1O + og) * 3 + 1]);
        vz += fmaf(a, sh_u[e * 3 + 2], sh_v[(e * M1O + og) * 3 + 2]);
      }
      const float sc = gate * 0.0625f;
      f1next[(n * M1O + og) * 3 + 0] = vx * sc;
      f1next[(n * M1O + og) * 3 + 1] = vy * sc;
      f1next[(n * M1O + og) * 3 + 2] = vz * sc;
    }
  }
}

__global__ void reduce_kernel(const float* __restrict__ f0c, float* __restrict__ out) {
  __shared__ float red[256];
  const int o = blockIdx.x;
  float s = 0.0f;
  for (int n = threadIdx.x; n < NTOT; n += 256) s += f0c[n * 32 + o];
  red[threadIdx.x] = s;
  __syncthreads();
  for (int w = 128; w > 0; w >>= 1) {
    if (threadIdx.x < w) red[threadIdx.x] += red[threadIdx.x + w];
    __syncthreads();
  }
  if (threadIdx.x == 0) out[o] = red[0] / (float)NTOT;
}

extern "C" void kernel_launch(void* const* d_in, const int* in_sizes, int n_in,
                              void* d_out, int out_size, void* d_ws, size_t ws_size,
                              hipStream_t stream) {
  const float* radii   = (const float*)d_in[0];
  const int*   nbr     = (const int*)d_in[1];
  const int*   charges = (const int*)d_in[2];
  const float* w1l[3] = {(const float*)d_in[3],  (const float*)d_in[8],  (const float*)d_in[13]};
  const float* b1l[3] = {(const float*)d_in[4],  (const float*)d_in[9],  (const float*)d_in[14]};
  const float* w2l[3] = {(const float*)d_in[5],  (const float*)d_in[10], (const float*)d_in[15]};
  const float* b2l[3] = {(const float*)d_in[6],  (const float*)d_in[11], (const float*)d_in[16]};
  const float* w3l[3] = {(const float*)d_in[7],  (const float*)d_in[12], (const float*)d_in[17]};

  char* ws = (char*)d_ws;
  size_t off = 0;
  float* f00 = (float*)(ws + off); off += NTOT * 4;            // 40000
  float* f0a = (float*)(ws + off); off += NTOT * 16 * 4;
  float* f1a = (float*)(ws + off); off += NTOT * 24 * 4;
  float* f0b = (float*)(ws + off); off += NTOT * 16 * 4;
  float* f1b = (float*)(ws + off); off += NTOT * 24 * 4;
  float* f0c = (float*)(ws + off); off += NTOT * 32 * 4;
  float* b2pad = (float*)(ws + off); off += 384 * 4;
  unsigned short* bt2  = (unsigned short*)(ws + off); off += (size_t)3 * 128 * 256 * 2;
  unsigned short* bt31 = (unsigned short*)(ws + off); off += (size_t)32  * 256 * 2;
  unsigned short* bt32 = (unsigned short*)(ws + off); off += (size_t)832 * 256 * 2;
  unsigned short* bt33 = (unsigned short*)(ws + off); off += (size_t)768 * 256 * 2;
  const unsigned short* bt3l[3] = {bt31, bt32, bt33};

  // dynamic segmentation: h1/h2 need ES*512 bytes total
  size_t remain = (ws_size > off) ? (ws_size - off) : 0;
  long es = (long)(remain / 512);
  es = (es / 64) * 64;
  if (es > EDGES) es = EDGES;
  if (es < 64) es = 64;
  unsigned short* h1b = (unsigned short*)(ws + off); off += (size_t)es * 128 * 2;
  unsigned short* h2b = (unsigned short*)(ws + off);

  prep_misc<<<(NTOT + 384 + 255) / 256, 256, 0, stream>>>(charges, b2l[0], b2l[1], b2l[2], f00, b2pad);
  prep_bt<<<128, 256, 0, stream>>>(w2l[0], 100, 100, 128, bt2);
  prep_bt<<<128, 256, 0, stream>>>(w2l[1], 100, 100, 128, bt2 + 32768);
  prep_bt<<<128, 256, 0, stream>>>(w2l[2], 100, 100, 128, bt2 + 65536);
  prep_bt<<<32,  256, 0, stream>>>(w3l[0], 100, 32,  32,  bt31);
  prep_bt<<<832, 256, 0, stream>>>(w3l[1], 100, 832, 832, bt32);
  prep_bt<<<768, 256, 0, stream>>>(w3l[2], 100, 768, 768, bt33);

  const float* f0p[4] = {f00, f0a, f0b, nullptr};
  const float* f1p[4] = {nullptr, f1a, f1b, nullptr};
  float* f0n[3] = {f0a, f0b, f0c};
  float* f1n[3] = {f1a, f1b, nullptr};

  for (int l = 0; l < 3; ++l) {
    for (long ee = 0; ee < EDGES; ee += es) {
      long cnt = EDGES - ee; if (cnt > es) cnt = es;
      int nblk = (int)(cnt / 64);
      k1_kernel<<<nblk, 256, 0, stream>>>(radii, w1l[l], b1l[l], h1b, (int)ee);
      k2_kernel<<<nblk, 256, 0, stream>>>(h1b, bt2 + l * 32768, b2pad + l * 128, h2b);
      if (l == 0)
        k3_kernel<1, 0, 16, 8, 8><<<nblk, 256, 0, stream>>>(radii, nbr, f0p[0], f1p[0],
            h2b, bt3l[0], f0n[0], f1n[0], (int)ee);
      else if (l == 1)
        k3_kernel<16, 8, 16, 8, 8><<<nblk, 256, 0, stream>>>(radii, nbr, f0p[1], f1p[1],
            h2b, bt3l[1], f0n[1], f1n[1], (int)ee);
      else
        k3_kernel<16, 8, 32, 0, 0><<<nblk, 256, 0, stream>>>(radii, nbr, f0p[2], f1p[2],
            h2b, bt3l[2], f0n[2], f1n[2], (int)ee);
    }
  }

  reduce_kernel<<<32, 256, 0, stream>>>(f0c, (float*)d_out);
}

// Round 3
// 679.792 us; speedup vs baseline: 2.9938x; 1.0632x over previous
//
#include <hip/hip_runtime.h>
#include <math.h>

// EQNetwork on MI355X — R3: one fused kernel per layer (basis+MLP+TP+scatter).
// A fragments live in registers (hoisted once; hi/lo K-split and all B chunks
// reuse them); B chunks are register-prefetched then LDS-staged (one 32 KB
// buffer); the tensor-product contraction runs directly on MFMA accumulators
// (C-layout: lane holds W[e=quad*4+r][col=16*b+ln15]; i-reduction = shfl_xor
// over 16/8 lanes). LDS ~74 KB -> 2 blocks/CU. Numerics identical to the
// R2-validated hi/lo bf16 weight-split scheme (absmax 3.7e-9).

#define NTOT  10000
#define EDGES 160000
#define HD    100
#define NBAS  10

typedef __attribute__((ext_vector_type(8))) short short8;
typedef __attribute__((ext_vector_type(4))) float float4v;

__device__ inline unsigned short f2bf(float x) {
  unsigned u = __builtin_bit_cast(unsigned, x);
  u += 0x7fffu + ((u >> 16) & 1u);          // RNE
  return (unsigned short)(u >> 16);
}
__device__ inline float bf2f(unsigned short b) {
  unsigned u = ((unsigned)b) << 16;
  return __builtin_bit_cast(float, u);
}

// LDS fragment read for MFMA 16x16x32 bf16. Tiles stored as rows of S 16B
// slots, physical slot = kb ^ (row & 15)  -> <=2-way bank aliasing (free).
__device__ inline short8 fragld(const unsigned short* lds, int rbase, int S, int kb, int lane) {
  int r = rbase + (lane & 15);
  int p = kb ^ (r & 15);
  return *(const short8*)(lds + (r * S + p) * 8);
}

// Split weight [Ks x Ns] (k-major) into bt[Nrows][256] bf16:
// bt[n][k'] = hi(w[k'][n]) for k'<128, lo(w[k'-128][n]) for k'>=128 (0-padded).
__global__ void prep_bt(const float* __restrict__ w, int Ks, int Ns, int Nrows,
                        unsigned short* __restrict__ bt) {
  int total = Nrows * 256;
  for (int g = blockIdx.x * 256 + threadIdx.x; g < total; g += gridDim.x * 256) {
    int n = g >> 8, kp = g & 255;
    int k = kp & 127;
    float v = (k < Ks && n < Ns) ? w[k * Ns + n] : 0.f;
    unsigned short hi = f2bf(v);
    bt[g] = (kp < 128) ? hi : f2bf(v - bf2f(hi));
  }
}

template<int M0I, int M1I, int M0O, int NG, int M1O>
__global__ __launch_bounds__(256, 2) void layer_fused(
    const float* __restrict__ radii, const int* __restrict__ nbr,
    const int* __restrict__ charges,
    const float* __restrict__ f0prev, const float* __restrict__ f1prev,
    const float* __restrict__ w1, const float* __restrict__ b1,
    const unsigned short* __restrict__ bt2, const float* __restrict__ b2,
    const unsigned short* __restrict__ bt3,
    float* __restrict__ f0next, float* __restrict__ f1next)
{
  constexpr int M0T = M0O + NG;
  constexpr int O   = M0T * M0I + M0T * M1I + M1O * M0I + 2 * M1O * M1I;
  constexpr int OFF01  = M0T * M0I;
  constexpr int OFF10  = OFF01 + M0T * M1I;
  constexpr int OFF11A = OFF10 + M1O * M0I;
  constexpr int OFF11B = OFF11A + M1O * M1I;
  constexpr int CW  = (O >= 64) ? 64 : 32;
  constexpr int NCH = O / CW;
  constexpr int AB  = (CW == 64) ? 4 : 2;     // e-blocks per wave, k3 part
  static_assert(O % CW == 0, "chunk must divide O");

  __shared__ __align__(16) unsigned short bufB[64 * 256];   // 32 KB: w2/w3 chunks
  __shared__ __align__(16) unsigned short bufA[64 * 128];   // 16 KB: h1 -> h2 -> w11 tables
  __shared__ float sh_s[64 * M0T];
  __shared__ float sh_a10[(M1O > 0) ? 64 * M1O : 1];
  __shared__ float sh_v[(M1O > 0) ? 64 * M1O * 3 : 1];
  __shared__ float sh_g0[(M0I > 1) ? 64 * 16 : 64];
  __shared__ float sh_p1[(M1I > 0) ? 64 * 8 : 1];
  __shared__ float sh_u[64 * 3];
  __shared__ float sh_r[64];
  __shared__ int   sh_idx[64];
  __shared__ float w1s[NBAS * HD];
  __shared__ float b1s[HD];
  __shared__ float b2s[128];

  const int tid  = threadIdx.x;
  const int lane = tid & 63, w = tid >> 6;
  const int quad = lane >> 4, ln15 = lane & 15;
  const int eg0  = blockIdx.x * 64;

  // ---- prefetch w2 chunk 0 (hidden under phase 0) ----
  short8 pref[8];
  {
    const short8* src = (const short8*)bt2;
    #pragma unroll
    for (int i = 0; i < 8; ++i) pref[i] = src[tid + 256 * i];
  }

  // ---- phase 0a: geometry, weight/bias staging, zero accumulators ----
  if (tid < 64) {
    float x = radii[(size_t)(eg0 + tid) * 3 + 0];
    float y = radii[(size_t)(eg0 + tid) * 3 + 1];
    float z = radii[(size_t)(eg0 + tid) * 3 + 2];
    float rr = sqrtf(x * x + y * y + z * z);
    float inv = 1.0f / (rr + 1e-8f);
    sh_u[tid * 3 + 0] = x * inv;
    sh_u[tid * 3 + 1] = y * inv;
    sh_u[tid * 3 + 2] = z * inv;
    sh_r[tid] = rr;
    sh_idx[tid] = nbr[eg0 + tid];
  }
  for (int p = tid; p < NBAS * HD; p += 256) w1s[p] = w1[p];
  if (tid < HD) b1s[tid] = b1[tid];
  if (tid < 128) b2s[tid] = (tid < HD) ? b2[tid] : 0.f;
  for (int p = tid; p < 64 * M0T; p += 256) sh_s[p] = 0.f;
  if constexpr (M1O > 0) {
    for (int p = tid; p < 64 * M1O; p += 256)     sh_a10[p] = 0.f;
    for (int p = tid; p < 64 * M1O * 3; p += 256) sh_v[p] = 0.f;
  }
  {
    short8 z = {0, 0, 0, 0, 0, 0, 0, 0};
    #pragma unroll
    for (int i = 0; i < 4; ++i) ((short8*)bufA)[tid + 256 * i] = z;
  }
  __syncthreads();

  // ---- phase 0b: h1 = relu(basis@w1+b1) -> bufA (bf16, A-swizzled); gathers ----
  {
    const int e = tid & 63, jg = tid >> 6;
    const float rr = sh_r[e];
    float bas[NBAS];
    constexpr float STEP = 5.0f / 9.0f;
    #pragma unroll
    for (int nb = 0; nb < NBAS; ++nb) {
      float d = (rr - (float)nb * STEP) / STEP;
      float c = cosf(1.5707964f * d);
      bas[nb] = (fabsf(d) < 1.0f) ? c * c : 0.0f;
    }
    for (int j = jg * 25; j < jg * 25 + 25; ++j) {
      float acc = b1s[j];
      #pragma unroll
      for (int nb = 0; nb < NBAS; ++nb) acc = fmaf(bas[nb], w1s[nb * HD + j], acc);
      int kb = j >> 3;
      bufA[(e * 16 + (kb ^ (e & 15))) * 8 + (j & 7)] = f2bf(fmaxf(acc, 0.f));
    }
  }
  if constexpr (M0I > 1) {
    for (int p = tid; p < 64 * 16; p += 256) {
      int e = p >> 4, i = p & 15;
      sh_g0[p] = 0.5f * f0prev[sh_idx[e] * M0I + i];
    }
  } else {
    if (tid < 64) sh_g0[tid] = 0.5f * ((float)charges[sh_idx[tid]] / 94.0f - 0.5f);
  }
  if constexpr (M1I > 0) {
    for (int p = tid; p < 64 * M1I; p += 256) {
      int e = p >> 3, i = p & 7;
      const float* g = f1prev + (size_t)(sh_idx[e] * M1I + i) * 3;
      sh_p1[p] = 0.5f * (g[0] * sh_u[e * 3] + g[1] * sh_u[e * 3 + 1] + g[2] * sh_u[e * 3 + 2]);
    }
  }
  // write prefetched w2c0 -> bufB (swizzled)
  #pragma unroll
  for (int i = 0; i < 8; ++i) {
    int g = tid + 256 * i; int row = g >> 5, kb = g & 31;
    ((short8*)bufB)[row * 32 + (kb ^ (row & 15))] = pref[i];
  }
  __syncthreads();

  // ---- hoist h1 A-fragments to registers (reused by both w2 chunks, hi+lo) ----
  short8 afr1[4][4];
  #pragma unroll
  for (int a = 0; a < 4; ++a)
    #pragma unroll
    for (int kk = 0; kk < 4; ++kk)
      afr1[a][kk] = fragld(bufA, a * 16, 16, kk * 4 + quad, lane);
  __syncthreads();   // all waves hoisted before anyone writes h2 into bufA

  // ---- k2 part: h2 = relu(h1@w2split+b2), two 64-col chunks ----
  #pragma unroll
  for (int t = 0; t < 2; ++t) {
    {  // prefetch next chunk: t==0 -> w2c1 (64 rows), t==1 -> w3c0 (CW rows)
      const short8* src = (t == 0) ? (const short8*)(bt2 + 16384) : (const short8*)bt3;
      const int ne = ((t == 0) ? 64 : CW) * 32;
      #pragma unroll
      for (int i = 0; i < 8; ++i)
        if (tid + 256 * i < ne) pref[i] = src[tid + 256 * i];
    }
    float4v acc[4];
    #pragma unroll
    for (int a = 0; a < 4; ++a) acc[a] = (float4v){0.f, 0.f, 0.f, 0.f};
    for (int ks = 0; ks < 8; ++ks) {
      short8 bf = fragld(bufB, w * 16, 32, ks * 4 + quad, lane);
      #pragma unroll
      for (int a = 0; a < 4; ++a)
        acc[a] = __builtin_amdgcn_mfma_f32_16x16x32_bf16(afr1[a][ks & 3], bf, acc[a], 0, 0, 0);
    }
    {  // epilogue: bf16 h2 into bufA at A-swizzled slots
      int n = t * 64 + w * 16 + ln15;
      float bb = b2s[n];
      int kb = n >> 3, j = n & 7;
      #pragma unroll
      for (int a = 0; a < 4; ++a)
        #pragma unroll
        for (int r = 0; r < 4; ++r) {
          int m = a * 16 + quad * 4 + r;
          bufA[(m * 16 + (kb ^ (m & 15))) * 8 + j] = f2bf(fmaxf(acc[a][r] + bb, 0.f));
        }
    }
    __syncthreads();
    {  // write prefetched chunk -> bufB
      const int ne = ((t == 0) ? 64 : CW) * 32;
      #pragma unroll
      for (int i = 0; i < 8; ++i)
        if (tid + 256 * i < ne) {
          int g = tid + 256 * i; int row = g >> 5, kb = g & 31;
          ((short8*)bufB)[row * 32 + (kb ^ (row & 15))] = pref[i];
        }
    }
    __syncthreads();
  }

  // ---- hoist h2 A-fragments; then (L2) build w11 tables over bufA ----
  const int eb3 = (CW == 64) ? 0 : (w & 1) * 2;
  const int colw = (CW == 64) ? w : (w >> 1);
  short8 afr2[AB][4];
  #pragma unroll
  for (int a = 0; a < AB; ++a)
    #pragma unroll
    for (int kk = 0; kk < 4; ++kk)
      afr2[a][kk] = fragld(bufA, (eb3 + a) * 16, 16, kk * 4 + quad, lane);

  if constexpr (M1O > 0 && M1I > 0) {
    __syncthreads();   // bufA reads done before table writes
    float4v* w11a = (float4v*)bufA;
    float4v* w11b = w11a + 512;
    for (int p = tid; p < 64 * M1I; p += 256) {
      int e = p >> 3, i = p & 7;
      const float* g = f1prev + (size_t)(sh_idx[e] * M1I + i) * 3;
      float gx = 0.5f * g[0], gy = 0.5f * g[1], gz = 0.5f * g[2];
      float ux = sh_u[e * 3], uy = sh_u[e * 3 + 1], uz = sh_u[e * 3 + 2];
      w11a[p] = (float4v){gx, gy, gz, 0.f};
      w11b[p] = (float4v){gy * uz - gz * uy, gz * ux - gx * uz, gx * uy - gy * ux, 0.f};
    }
    __syncthreads();
  }

  // ---- contraction operand registers (once per block) ----
  float g0v[AB * 4];
  float p1v[(M1I > 0) ? AB * 4 : 1];
  #pragma unroll
  for (int a = 0; a < AB; ++a)
    #pragma unroll
    for (int r = 0; r < 4; ++r) {
      int e = (eb3 + a) * 16 + quad * 4 + r;
      g0v[a * 4 + r] = (M0I > 1) ? sh_g0[e * 16 + ln15] : sh_g0[e];
      if constexpr (M1I > 0) p1v[a * 4 + r] = sh_p1[e * 8 + (ln15 & 7)];
    }

  // ---- k3 part: W = h2@w3split per chunk, contracted from accumulators ----
  for (int c = 0; c < NCH; ++c) {
    const int c0 = c * CW;
    if (c + 1 < NCH) {
      const short8* src = (const short8*)(bt3 + (size_t)(c + 1) * CW * 256);
      #pragma unroll
      for (int i = 0; i < (CW * 32) / 256; ++i) pref[i] = src[tid + 256 * i];
    }
    float4v acc[AB];
    #pragma unroll
    for (int a = 0; a < AB; ++a) acc[a] = (float4v){0.f, 0.f, 0.f, 0.f};
    for (int ks = 0; ks < 8; ++ks) {
      short8 bf = fragld(bufB, colw * 16, 32, ks * 4 + quad, lane);
      #pragma unroll
      for (int a = 0; a < AB; ++a)
        acc[a] = __builtin_amdgcn_mfma_f32_16x16x32_bf16(afr2[a][ks & 3], bf, acc[a], 0, 0, 0);
    }

    // contraction: lane holds W[e=(eb3+a)*16+quad*4+r][col=colw*16+ln15] (+c0)
    if constexpr (M0I == 1) {
      const int gcol = colw * 16 + ln15;   // NCH==1, c0==0
      #pragma unroll
      for (int a = 0; a < AB; ++a)
        #pragma unroll
        for (int r = 0; r < 4; ++r) {
          int e = (eb3 + a) * 16 + quad * 4 + r;
          float val = acc[a][r] * g0v[a * 4 + r];
          if (gcol < OFF01) sh_s[e * M0T + gcol] += val;
          else              sh_a10[e * M1O + (gcol - OFF01)] += val;
        }
    } else {
      if (c0 < OFF01) {                     // 0->0: reduce over i=ln15 (16)
        const int o = (c0 >> 4) + colw;
        float part[AB * 4];
        #pragma unroll
        for (int k = 0; k < AB * 4; ++k) part[k] = acc[k >> 2][k & 3] * g0v[k];
        #pragma unroll
        for (int off = 1; off < 16; off <<= 1)
          #pragma unroll
          for (int k = 0; k < AB * 4; ++k) part[k] += __shfl_xor(part[k], off);
        if (ln15 == 0) {
          #pragma unroll
          for (int k = 0; k < AB * 4; ++k) {
            int e = (eb3 + (k >> 2)) * 16 + quad * 4 + (k & 3);
            sh_s[e * M0T + o] += part[k];
          }
        }
      } else if (c0 < OFF10) {              // 1->0: reduce over i=ln15&7 (8)
        const int o = ((c0 - OFF01) >> 3) + colw * 2 + (ln15 >> 3);
        float part[AB * 4];
        #pragma unroll
        for (int k = 0; k < AB * 4; ++k) part[k] = acc[k >> 2][k & 3] * p1v[k];
        #pragma unroll
        for (int off = 1; off < 8; off <<= 1)
          #pragma unroll
          for (int k = 0; k < AB * 4; ++k) part[k] += __shfl_xor(part[k], off);
        if ((ln15 & 7) == 0) {
          #pragma unroll
          for (int k = 0; k < AB * 4; ++k) {
            int e = (eb3 + (k >> 2)) * 16 + quad * 4 + (k & 3);
            sh_s[e * M0T + o] += part[k];
          }
        }
      } else if constexpr (M1O > 0) {
        if (c0 < OFF11A) {                  // 0->1: reduce over i=ln15 (16)
          const int o = ((c0 - OFF10) >> 4) + colw;
          float part[AB * 4];
          #pragma unroll
          for (int k = 0; k < AB * 4; ++k) part[k] = acc[k >> 2][k & 3] * g0v[k];
          #pragma unroll
          for (int off = 1; off < 16; off <<= 1)
            #pragma unroll
            for (int k = 0; k < AB * 4; ++k) part[k] += __shfl_xor(part[k], off);
          if (ln15 == 0) {
            #pragma unroll
            for (int k = 0; k < AB * 4; ++k) {
              int e = (eb3 + (k >> 2)) * 16 + quad * 4 + (k & 3);
              sh_a10[e * M1O + o] += part[k];
            }
          }
        } else {                            // 1->1 (a/b): vector, reduce over 8
          const bool is_b = (c0 >= OFF11B);
          const int o = colw * 2 + (ln15 >> 3);
          const float4v* tb = ((const float4v*)bufA) + (is_b ? 512 : 0);
          float px[AB * 4], py[AB * 4], pz[AB * 4];
          #pragma unroll
          for (int k = 0; k < AB * 4; ++k) {
            int e = (eb3 + (k >> 2)) * 16 + quad * 4 + (k & 3);
            float4v t = tb[e * 8 + (ln15 & 7)];
            float a_ = acc[k >> 2][k & 3];
            px[k] = a_ * t[0]; py[k] = a_ * t[1]; pz[k] = a_ * t[2];
          }
          #pragma unroll
          for (int off = 1; off < 8; off <<= 1)
            #pragma unroll
            for (int k = 0; k < AB * 4; ++k) {
              px[k] += __shfl_xor(px[k], off);
              py[k] += __shfl_xor(py[k], off);
              pz[k] += __shfl_xor(pz[k], off);
            }
          if ((ln15 & 7) == 0) {
            #pragma unroll
            for (int k = 0; k < AB * 4; ++k) {
              int e = (eb3 + (k >> 2)) * 16 + quad * 4 + (k & 3);
              sh_v[(e * M1O + o) * 3 + 0] += px[k];
              sh_v[(e * M1O + o) * 3 + 1] += py[k];
              sh_v[(e * M1O + o) * 3 + 2] += pz[k];
            }
          }
        }
      }
    }

    if (c + 1 < NCH) {
      __syncthreads();
      #pragma unroll
      for (int i = 0; i < (CW * 32) / 256; ++i) {
        int g = tid + 256 * i; int row = g >> 5, kb = g & 31;
        ((short8*)bufB)[row * 32 + (kb ^ (row & 15))] = pref[i];
      }
      __syncthreads();
    }
  }
  __syncthreads();

  // ---- finalize: mean over K=16, relu / sigmoid gating, write ----
  if (tid < 4 * M0T) {
    const int nl = tid / M0T;
    const int o  = tid - nl * M0T;
    float ssum = 0.0f;
    for (int k = 0; k < 16; ++k) ssum += sh_s[(nl * 16 + k) * M0T + o];
    const float sm = ssum * 0.0625f;
    const int n = blockIdx.x * 4 + nl;
    if (o < M0O) {
      f0next[n * M0O + o] = fmaxf(sm, 0.0f);
    } else if constexpr (M1O > 0) {
      const int og = o - M0O;
      const float gate = 1.0f / (1.0f + expf(-sm));
      float vx = 0.f, vy = 0.f, vz = 0.f;
      for (int k = 0; k < 16; ++k) {
        int e = nl * 16 + k;
        float a = sh_a10[e * M1O + og];
        vx += fmaf(a, sh_u[e * 3 + 0], sh_v[(e * M1O + og) * 3 + 0]);
        vy += fmaf(a, sh_u[e * 3 + 1], sh_v[(e * M1O + og) * 3 + 1]);
        vz += fmaf(a, sh_u[e * 3 + 2], sh_v[(e * M1O + og) * 3 + 2]);
      }
      const float sc = gate * 0.0625f;
      f1next[(n * M1O + og) * 3 + 0] = vx * sc;
      f1next[(n * M1O + og) * 3 + 1] = vy * sc;
      f1next[(n * M1O + og) * 3 + 2] = vz * sc;
    }
  }
}

__global__ void reduce_kernel(const float* __restrict__ f0c, float* __restrict__ out) {
  __shared__ float red[256];
  const int o = blockIdx.x;
  float s = 0.0f;
  for (int n = threadIdx.x; n < NTOT; n += 256) s += f0c[n * 32 + o];
  red[threadIdx.x] = s;
  __syncthreads();
  for (int w = 128; w > 0; w >>= 1) {
    if (threadIdx.x < w) red[threadIdx.x] += red[threadIdx.x + w];
    __syncthreads();
  }
  if (threadIdx.x == 0) out[o] = red[0] / (float)NTOT;
}

extern "C" void kernel_launch(void* const* d_in, const int* in_sizes, int n_in,
                              void* d_out, int out_size, void* d_ws, size_t ws_size,
                              hipStream_t stream) {
  const float* radii   = (const float*)d_in[0];
  const int*   nbr     = (const int*)d_in[1];
  const int*   charges = (const int*)d_in[2];
  const float* w1l[3] = {(const float*)d_in[3],  (const float*)d_in[8],  (const float*)d_in[13]};
  const float* b1l[3] = {(const float*)d_in[4],  (const float*)d_in[9],  (const float*)d_in[14]};
  const float* w2l[3] = {(const float*)d_in[5],  (const float*)d_in[10], (const float*)d_in[15]};
  const float* b2l[3] = {(const float*)d_in[6],  (const float*)d_in[11], (const float*)d_in[16]};
  const float* w3l[3] = {(const float*)d_in[7],  (const float*)d_in[12], (const float*)d_in[17]};

  char* ws = (char*)d_ws;
  size_t off = 0;
  float* f0a = (float*)(ws + off); off += (size_t)NTOT * 16 * 4;
  float* f1a = (float*)(ws + off); off += (size_t)NTOT * 24 * 4;
  float* f0b = (float*)(ws + off); off += (size_t)NTOT * 16 * 4;
  float* f1b = (float*)(ws + off); off += (size_t)NTOT * 24 * 4;
  float* f0c = (float*)(ws + off); off += (size_t)NTOT * 32 * 4;
  unsigned short* bt2  = (unsigned short*)(ws + off); off += (size_t)3 * 128 * 256 * 2;
  unsigned short* bt31 = (unsigned short*)(ws + off); off += (size_t)32  * 256 * 2;
  unsigned short* bt32 = (unsigned short*)(ws + off); off += (size_t)832 * 256 * 2;
  unsigned short* bt33 = (unsigned short*)(ws + off); off += (size_t)768 * 256 * 2;

  prep_bt<<<128, 256, 0, stream>>>(w2l[0], 100, 100, 128, bt2);
  prep_bt<<<128, 256, 0, stream>>>(w2l[1], 100, 100, 128, bt2 + 32768);
  prep_bt<<<128, 256, 0, stream>>>(w2l[2], 100, 100, 128, bt2 + 65536);
  prep_bt<<<32,  256, 0, stream>>>(w3l[0], 100, 32,  32,  bt31);
  prep_bt<<<832, 256, 0, stream>>>(w3l[1], 100, 832, 832, bt32);
  prep_bt<<<768, 256, 0, stream>>>(w3l[2], 100, 768, 768, bt33);

  constexpr int NBLK = EDGES / 64;   // 2500

  layer_fused<1, 0, 16, 8, 8><<<NBLK, 256, 0, stream>>>(
      radii, nbr, charges, nullptr, nullptr,
      w1l[0], b1l[0], bt2, b2l[0], bt31, f0a, f1a);

  layer_fused<16, 8, 16, 8, 8><<<NBLK, 256, 0, stream>>>(
      radii, nbr, charges, f0a, f1a,
      w1l[1], b1l[1], bt2 + 32768, b2l[1], bt32, f0b, f1b);

  layer_fused<16, 8, 32, 0, 0><<<NBLK, 256, 0, stream>>>(
      radii, nbr, charges, f0b, f1b,
      w1l[2], b1l[2], bt2 + 65536, b2l[2], bt33, f0c, nullptr);

  reduce_kernel<<<32, 256, 0, stream>>>(f0c, (float*)d_out);
}

// Round 4
// 464.846 us; speedup vs baseline: 4.3781x; 1.4624x over previous
//
#include <hip/hip_runtime.h>
#include <math.h>

// EQNetwork on MI355X — R4: swapped MFMA orientation D[m=weight-col][n=edge].
// Wave-invariant operand = own 16 edges (16 VGPRs, was 128 -> kills the R3
// scratch spills: 89 MB/dispatch scratch writes). TP contraction's i-index
// now lives in the row (quad*4+reg) dim: reduce = 3 reg-FMAs + 1-2 shuffles
// (was 4-step x16-value butterflies). Weight images pre-permuted in prep_bt
// so staging is a linear 32 KB copy. Numerics = R2/R3-validated hi/lo bf16
// weight split folded into K=256 (absmax 3.7e-9).

#define NTOT  10000
#define EDGES 160000
#define HD    100
#define NBAS  10

typedef __attribute__((ext_vector_type(8))) short short8;
typedef __attribute__((ext_vector_type(4))) float float4v;

__device__ inline unsigned short f2bf(float x) {
  unsigned u = __builtin_bit_cast(unsigned, x);
  u += 0x7fffu + ((u >> 16) & 1u);          // RNE
  return (unsigned short)(u >> 16);
}
__device__ inline float bf2f(unsigned short b) {
  unsigned u = ((unsigned)b) << 16;
  return __builtin_bit_cast(float, u);
}

// LDS fragment read, MFMA 16x16x32 bf16. Tile = rows of S 16B-slots,
// physical slot = kb ^ (row & 15) -> <=2-way bank aliasing (free).
__device__ inline short8 fragld(const unsigned short* lds, int rbase, int S, int kb, int lane) {
  int r = rbase + (lane & 15);
  int p = kb ^ (r & 15);
  return *(const short8*)(lds + (r * S + p) * 8);
}

// Emit weight image in final LDS layout: groups of 64 rows (weight cols),
// 2048 short8-slots per group, slot = row*32 + (kb ^ (row&15)), element j of
// slot = k' = kb*8+j. k'<128 -> hi(w[k'][n]), k'>=128 -> lo(w[k'-128][n]).
__global__ void prep_bt(const float* __restrict__ w, int Ks, int Ns, int Ngrp,
                        unsigned short* __restrict__ bt) {
  int total = Ngrp * 2048 * 8;
  for (int g = blockIdx.x * 256 + threadIdx.x; g < total; g += gridDim.x * 256) {
    int slot = g >> 3, j = g & 7;
    int grp = slot >> 11, rem = slot & 2047;
    int row = rem >> 5, x = rem & 31;
    int kb = x ^ (row & 15);
    int kp = kb * 8 + j;
    int k = kp & 127;
    int n = grp * 64 + row;
    float v = (k < Ks && n < Ns) ? w[k * Ns + n] : 0.f;
    unsigned short hi = f2bf(v);
    bt[g] = (kp < 128) ? hi : f2bf(v - bf2f(hi));
  }
}

template<int M0I, int M1I, int M0O, int NG, int M1O>
__global__ __launch_bounds__(256, 2) void layer_fused(
    const float* __restrict__ radii, const int* __restrict__ nbr,
    const int* __restrict__ charges,
    const float* __restrict__ f0prev, const float* __restrict__ f1prev,
    const float* __restrict__ w1, const float* __restrict__ b1,
    const unsigned short* __restrict__ bt2, const float* __restrict__ b2,
    const unsigned short* __restrict__ bt3,
    float* __restrict__ f0next, float* __restrict__ f1next)
{
  constexpr int M0T = M0O + NG;
  constexpr int O   = M0T * M0I + M0T * M1I + M1O * M0I + 2 * M1O * M1I;
  constexpr int OFF01  = M0T * M0I;
  constexpr int OFF10  = OFF01 + M0T * M1I;
  constexpr int OFF11A = OFF10 + M1O * M0I;
  constexpr int OFF11B = OFF11A + M1O * M1I;
  constexpr int NCH = (O + 63) / 64;      // L1:1 (zero-padded), L2:13, L3:12

  __shared__ __align__(16) unsigned short bufB[64 * 256];   // 32 KB weight chunk
  __shared__ __align__(16) unsigned short bufA[64 * 128];   // 16 KB h1 -> h2 -> w11 tables
  __shared__ float sh_s[64 * M0T];
  __shared__ float sh_a10[(M1O > 0) ? 64 * M1O : 1];
  __shared__ float sh_v[(M1O > 0) ? 64 * M1O * 3 : 1];
  __shared__ float sh_g0[(M0I > 1) ? 64 * 16 : 64];
  __shared__ float sh_p1[(M1I > 0) ? 64 * 8 : 1];
  __shared__ float sh_u[64 * 3];
  __shared__ float sh_r[64];
  __shared__ int   sh_idx[64];
  __shared__ float w1s[NBAS * HD];
  __shared__ float b1s[HD];
  __shared__ float b2s[128];

  const int tid  = threadIdx.x;
  const int lane = tid & 63, w = tid >> 6;
  const int quad = lane >> 4, ln15 = lane & 15;
  const int eg0  = blockIdx.x * 64;
  const int e_own = w * 16 + ln15;     // this lane's edge in swapped orientation

  // ---- prefetch w2 group 0 (hidden under phase 0) ----
  short8 pref[8];
  {
    const short8* src = (const short8*)bt2;
    #pragma unroll
    for (int i = 0; i < 8; ++i) pref[i] = src[tid + 256 * i];
  }

  // ---- phase 0a ----
  if (tid < 64) {
    float x = radii[(size_t)(eg0 + tid) * 3 + 0];
    float y = radii[(size_t)(eg0 + tid) * 3 + 1];
    float z = radii[(size_t)(eg0 + tid) * 3 + 2];
    float rr = sqrtf(x * x + y * y + z * z);
    float inv = 1.0f / (rr + 1e-8f);
    sh_u[tid * 3 + 0] = x * inv;
    sh_u[tid * 3 + 1] = y * inv;
    sh_u[tid * 3 + 2] = z * inv;
    sh_r[tid] = rr;
    sh_idx[tid] = nbr[eg0 + tid];
  }
  for (int p = tid; p < NBAS * HD; p += 256) w1s[p] = w1[p];
  if (tid < HD) b1s[tid] = b1[tid];
  if (tid < 128) b2s[tid] = (tid < HD) ? b2[tid] : 0.f;
  for (int p = tid; p < 64 * M0T; p += 256) sh_s[p] = 0.f;
  if constexpr (M1O > 0) {
    for (int p = tid; p < 64 * M1O; p += 256)     sh_a10[p] = 0.f;
    for (int p = tid; p < 64 * M1O * 3; p += 256) sh_v[p] = 0.f;
  }
  {
    short8 z = {0, 0, 0, 0, 0, 0, 0, 0};
    #pragma unroll
    for (int i = 0; i < 4; ++i) ((short8*)bufA)[tid + 256 * i] = z;
  }
  __syncthreads();

  // ---- phase 0b: h1 into bufA (A-swizzled bf16); gathers ----
  {
    const int e = tid & 63, jg = tid >> 6;
    const float rr = sh_r[e];
    float bas[NBAS];
    constexpr float STEP = 5.0f / 9.0f;
    #pragma unroll
    for (int nb = 0; nb < NBAS; ++nb) {
      float d = (rr - (float)nb * STEP) / STEP;
      float c = cosf(1.5707964f * d);
      bas[nb] = (fabsf(d) < 1.0f) ? c * c : 0.0f;
    }
    for (int j = jg * 25; j < jg * 25 + 25; ++j) {
      float acc = b1s[j];
      #pragma unroll
      for (int nb = 0; nb < NBAS; ++nb) acc = fmaf(bas[nb], w1s[nb * HD + j], acc);
      int kb = j >> 3;
      bufA[(e * 16 + (kb ^ (e & 15))) * 8 + (j & 7)] = f2bf(fmaxf(acc, 0.f));
    }
  }
  if constexpr (M0I > 1) {
    for (int p = tid; p < 64 * 16; p += 256) {
      int e = p >> 4, i = p & 15;
      sh_g0[p] = 0.5f * f0prev[sh_idx[e] * M0I + i];
    }
  } else {
    if (tid < 64) sh_g0[tid] = 0.5f * ((float)charges[sh_idx[tid]] / 94.0f - 0.5f);
  }
  if constexpr (M1I > 0) {
    for (int p = tid; p < 64 * M1I; p += 256) {
      int e = p >> 3, i = p & 7;
      const float* g = f1prev + (size_t)(sh_idx[e] * M1I + i) * 3;
      sh_p1[p] = 0.5f * (g[0] * sh_u[e * 3] + g[1] * sh_u[e * 3 + 1] + g[2] * sh_u[e * 3 + 2]);
    }
  }
  // write prefetched w2 group 0 -> bufB (linear: image pre-permuted)
  #pragma unroll
  for (int i = 0; i < 8; ++i) ((short8*)bufB)[tid + 256 * i] = pref[i];
  __syncthreads();

  // ---- hoist this wave's h1 B-fragments (its own 16 edges) ----
  short8 h1f[4];
  #pragma unroll
  for (int kk = 0; kk < 4; ++kk) h1f[kk] = fragld(bufA, w * 16, 16, kk * 4 + quad, lane);

  // ---- k2: h2 = relu(h1 @ w2split + b2), D[m=col][n=edge] ----
  #pragma unroll
  for (int t = 0; t < 2; ++t) {
    {  // prefetch: t==0 -> w2 group 1, t==1 -> w3 chunk 0
      const short8* src = (t == 0) ? (const short8*)(bt2 + 16384) : (const short8*)bt3;
      #pragma unroll
      for (int i = 0; i < 8; ++i) pref[i] = src[tid + 256 * i];
    }
    float4v acc[4];
    #pragma unroll
    for (int mt = 0; mt < 4; ++mt) acc[mt] = (float4v){0.f, 0.f, 0.f, 0.f};
    for (int ks = 0; ks < 8; ++ks) {
      #pragma unroll
      for (int mt = 0; mt < 4; ++mt) {
        short8 af = fragld(bufB, mt * 16, 32, ks * 4 + quad, lane);
        acc[mt] = __builtin_amdgcn_mfma_f32_16x16x32_bf16(af, h1f[ks & 3], acc[mt], 0, 0, 0);
      }
    }
    // epilogue: h2[e_own][col] -> bufA (paired u32 writes; own rows only)
    #pragma unroll
    for (int mt = 0; mt < 4; ++mt)
      #pragma unroll
      for (int p = 0; p < 2; ++p) {
        int col = t * 64 + mt * 16 + quad * 4 + 2 * p;
        unsigned lo = f2bf(fmaxf(acc[mt][2 * p]     + b2s[col],     0.f));
        unsigned hi = f2bf(fmaxf(acc[mt][2 * p + 1] + b2s[col + 1], 0.f));
        int kb = col >> 3, j = col & 7;
        *(unsigned*)&bufA[(e_own * 16 + (kb ^ (e_own & 15))) * 8 + j] = lo | (hi << 16);
      }
    __syncthreads();
    #pragma unroll
    for (int i = 0; i < 8; ++i) ((short8*)bufB)[tid + 256 * i] = pref[i];
    __syncthreads();
  }

  // ---- hoist h2 B-fragments; contraction operand regs ----
  short8 h2f[4];
  #pragma unroll
  for (int kk = 0; kk < 4; ++kk) h2f[kk] = fragld(bufA, w * 16, 16, kk * 4 + quad, lane);

  float g0r[4] = {0.f, 0.f, 0.f, 0.f};
  float p1r[4] = {0.f, 0.f, 0.f, 0.f};
  if constexpr (M0I > 1) {
    #pragma unroll
    for (int r = 0; r < 4; ++r) g0r[r] = sh_g0[e_own * 16 + quad * 4 + r];
  } else {
    g0r[0] = sh_g0[e_own];
  }
  if constexpr (M1I > 0) {
    #pragma unroll
    for (int r = 0; r < 4; ++r) p1r[r] = sh_p1[e_own * 8 + (quad & 1) * 4 + r];
  }

  // ---- (L2) build w11a/w11b tables over bufA ----
  if constexpr (M1O > 0 && M1I > 0) {
    __syncthreads();
    float4v* w11a = (float4v*)bufA;
    float4v* w11b = w11a + 512;
    for (int p = tid; p < 64 * M1I; p += 256) {
      int e = p >> 3, i = p & 7;
      const float* g = f1prev + (size_t)(sh_idx[e] * M1I + i) * 3;
      float gx = 0.5f * g[0], gy = 0.5f * g[1], gz = 0.5f * g[2];
      float ux = sh_u[e * 3], uy = sh_u[e * 3 + 1], uz = sh_u[e * 3 + 2];
      w11a[p] = (float4v){gx, gy, gz, 0.f};
      w11b[p] = (float4v){gy * uz - gz * uy, gz * ux - gx * uz, gx * uy - gy * ux, 0.f};
    }
    __syncthreads();
  }

  // ---- k3: W^T chunks via MFMA + fused contraction ----
  for (int c = 0; c < NCH; ++c) {
    const int c0 = c * 64;
    if (c + 1 < NCH) {
      const short8* src = (const short8*)(bt3 + (size_t)(c + 1) * 16384);
      #pragma unroll
      for (int i = 0; i < 8; ++i) pref[i] = src[tid + 256 * i];
    }
    float4v acc[4];
    #pragma unroll
    for (int mt = 0; mt < 4; ++mt) acc[mt] = (float4v){0.f, 0.f, 0.f, 0.f};
    for (int ks = 0; ks < 8; ++ks) {
      #pragma unroll
      for (int mt = 0; mt < 4; ++mt) {
        short8 af = fragld(bufB, mt * 16, 32, ks * 4 + quad, lane);
        acc[mt] = __builtin_amdgcn_mfma_f32_16x16x32_bf16(af, h2f[ks & 3], acc[mt], 0, 0, 0);
      }
    }

    // lane holds W[e_own][col = c0 + mt*16 + quad*4 + r]
    if constexpr (M0I == 1) {
      #pragma unroll
      for (int mt = 0; mt < 2; ++mt)            // cols 0..31 real, 32..63 pad
        #pragma unroll
        for (int r = 0; r < 4; ++r) {
          int col = mt * 16 + quad * 4 + r;
          float val = acc[mt][r] * g0r[0];
          if (col < OFF01) sh_s[e_own * M0T + col] += val;
          else             sh_a10[e_own * M1O + (col - OFF01)] += val;
        }
    } else {
      if (c0 < OFF01) {                         // 0->0: i = quad*4+r (16-wide)
        float part[4];
        #pragma unroll
        for (int mt = 0; mt < 4; ++mt)
          part[mt] = fmaf(acc[mt][0], g0r[0], fmaf(acc[mt][1], g0r[1],
                     fmaf(acc[mt][2], g0r[2], acc[mt][3] * g0r[3])));
        #pragma unroll
        for (int mt = 0; mt < 4; ++mt) {
          part[mt] += __shfl_xor(part[mt], 16);
          part[mt] += __shfl_xor(part[mt], 32);
        }
        if (quad == 0) {
          #pragma unroll
          for (int mt = 0; mt < 4; ++mt)
            sh_s[e_own * M0T + (c0 >> 4) + mt] += part[mt];
        }
      } else if (c0 < OFF10) {                  // 1->0: i = (quad&1)*4+r (8-wide)
        float part[4];
        #pragma unroll
        for (int mt = 0; mt < 4; ++mt)
          part[mt] = fmaf(acc[mt][0], p1r[0], fmaf(acc[mt][1], p1r[1],
                     fmaf(acc[mt][2], p1r[2], acc[mt][3] * p1r[3])));
        #pragma unroll
        for (int mt = 0; mt < 4; ++mt) part[mt] += __shfl_xor(part[mt], 16);
        if ((quad & 1) == 0) {
          #pragma unroll
          for (int mt = 0; mt < 4; ++mt)
            sh_s[e_own * M0T + ((c0 - OFF01) >> 3) + 2 * mt + (quad >> 1)] += part[mt];
        }
      } else if constexpr (M1O > 0) {
        if (c0 < OFF11A) {                      // 0->1: like 0->0, target a10
          float part[4];
          #pragma unroll
          for (int mt = 0; mt < 4; ++mt)
            part[mt] = fmaf(acc[mt][0], g0r[0], fmaf(acc[mt][1], g0r[1],
                       fmaf(acc[mt][2], g0r[2], acc[mt][3] * g0r[3])));
          #pragma unroll
          for (int mt = 0; mt < 4; ++mt) {
            part[mt] += __shfl_xor(part[mt], 16);
            part[mt] += __shfl_xor(part[mt], 32);
          }
          if (quad == 0) {
            #pragma unroll
            for (int mt = 0; mt < 4; ++mt)
              sh_a10[e_own * M1O + ((c0 - OFF10) >> 4) + mt] += part[mt];
          }
        } else {                                // 1->1 a/b: vector, 8-wide
          const bool is_b = (c0 >= OFF11B);
          const float4v* tb = ((const float4v*)bufA) + (is_b ? 512 : 0);
          float4v tr[4];
          #pragma unroll
          for (int r = 0; r < 4; ++r) tr[r] = tb[e_own * 8 + (quad & 1) * 4 + r];
          float px[4], py[4], pz[4];
          #pragma unroll
          for (int mt = 0; mt < 4; ++mt) {
            px[mt] = fmaf(acc[mt][0], tr[0][0], fmaf(acc[mt][1], tr[1][0],
                     fmaf(acc[mt][2], tr[2][0], acc[mt][3] * tr[3][0])));
            py[mt] = fmaf(acc[mt][0], tr[0][1], fmaf(acc[mt][1], tr[1][1],
                     fmaf(acc[mt][2], tr[2][1], acc[mt][3] * tr[3][1])));
            pz[mt] = fmaf(acc[mt][0], tr[0][2], fmaf(acc[mt][1], tr[1][2],
                     fmaf(acc[mt][2], tr[2][2], acc[mt][3] * tr[3][2])));
          }
          #pragma unroll
          for (int mt = 0; mt < 4; ++mt) {
            px[mt] += __shfl_xor(px[mt], 16);
            py[mt] += __shfl_xor(py[mt], 16);
            pz[mt] += __shfl_xor(pz[mt], 16);
          }
          if ((quad & 1) == 0) {
            #pragma unroll
            for (int mt = 0; mt < 4; ++mt) {
              int o = ((c0 - (is_b ? OFF11B : OFF11A)) >> 3) + 2 * mt + (quad >> 1);
              sh_v[(e_own * M1O + o) * 3 + 0] += px[mt];
              sh_v[(e_own * M1O + o) * 3 + 1] += py[mt];
              sh_v[(e_own * M1O + o) * 3 + 2] += pz[mt];
            }
          }
        }
      }
    }

    if (c + 1 < NCH) {
      __syncthreads();
      #pragma unroll
      for (int i = 0; i < 8; ++i) ((short8*)bufB)[tid + 256 * i] = pref[i];
      __syncthreads();
    }
  }
  __syncthreads();

  // ---- finalize: mean over K=16, relu / sigmoid gating, write ----
  if (tid < 4 * M0T) {
    const int nl = tid / M0T;
    const int o  = tid - nl * M0T;
    float ssum = 0.0f;
    for (int k = 0; k < 16; ++k) ssum += sh_s[(nl * 16 + k) * M0T + o];
    const float sm = ssum * 0.0625f;
    const int n = blockIdx.x * 4 + nl;
    if (o < M0O) {
      f0next[n * M0O + o] = fmaxf(sm, 0.0f);
    } else if constexpr (M1O > 0) {
      const int og = o - M0O;
      const float gate = 1.0f / (1.0f + expf(-sm));
      float vx = 0.f, vy = 0.f, vz = 0.f;
      for (int k = 0; k < 16; ++k) {
        int e = nl * 16 + k;
        float a = sh_a10[e * M1O + og];
        vx += fmaf(a, sh_u[e * 3 + 0], sh_v[(e * M1O + og) * 3 + 0]);
        vy += fmaf(a, sh_u[e * 3 + 1], sh_v[(e * M1O + og) * 3 + 1]);
        vz += fmaf(a, sh_u[e * 3 + 2], sh_v[(e * M1O + og) * 3 + 2]);
      }
      const float sc = gate * 0.0625f;
      f1next[(n * M1O + og) * 3 + 0] = vx * sc;
      f1next[(n * M1O + og) * 3 + 1] = vy * sc;
      f1next[(n * M1O + og) * 3 + 2] = vz * sc;
    }
  }
}

__global__ void reduce_kernel(const float* __restrict__ f0c, float* __restrict__ out) {
  __shared__ float red[256];
  const int o = blockIdx.x;
  float s = 0.0f;
  for (int n = threadIdx.x; n < NTOT; n += 256) s += f0c[n * 32 + o];
  red[threadIdx.x] = s;
  __syncthreads();
  for (int w = 128; w > 0; w >>= 1) {
    if (threadIdx.x < w) red[threadIdx.x] += red[threadIdx.x + w];
    __syncthreads();
  }
  if (threadIdx.x == 0) out[o] = red[0] / (float)NTOT;
}

extern "C" void kernel_launch(void* const* d_in, const int* in_sizes, int n_in,
                              void* d_out, int out_size, void* d_ws, size_t ws_size,
                              hipStream_t stream) {
  const float* radii   = (const float*)d_in[0];
  const int*   nbr     = (const int*)d_in[1];
  const int*   charges = (const int*)d_in[2];
  const float* w1l[3] = {(const float*)d_in[3],  (const float*)d_in[8],  (const float*)d_in[13]};
  const float* b1l[3] = {(const float*)d_in[4],  (const float*)d_in[9],  (const float*)d_in[14]};
  const float* w2l[3] = {(const float*)d_in[5],  (const float*)d_in[10], (const float*)d_in[15]};
  const float* b2l[3] = {(const float*)d_in[6],  (const float*)d_in[11], (const float*)d_in[16]};
  const float* w3l[3] = {(const float*)d_in[7],  (const float*)d_in[12], (const float*)d_in[17]};

  char* ws = (char*)d_ws;
  size_t off = 0;
  float* f0a = (float*)(ws + off); off += (size_t)NTOT * 16 * 4;
  float* f1a = (float*)(ws + off); off += (size_t)NTOT * 24 * 4;
  float* f0b = (float*)(ws + off); off += (size_t)NTOT * 16 * 4;
  float* f1b = (float*)(ws + off); off += (size_t)NTOT * 24 * 4;
  float* f0c = (float*)(ws + off); off += (size_t)NTOT * 32 * 4;
  unsigned short* bt2  = (unsigned short*)(ws + off); off += (size_t)3 * 2 * 16384 * 2;
  unsigned short* bt31 = (unsigned short*)(ws + off); off += (size_t)1  * 16384 * 2;
  unsigned short* bt32 = (unsigned short*)(ws + off); off += (size_t)13 * 16384 * 2;
  unsigned short* bt33 = (unsigned short*)(ws + off); off += (size_t)12 * 16384 * 2;

  prep_bt<<<128, 256, 0, stream>>>(w2l[0], 100, 100, 2, bt2);
  prep_bt<<<128, 256, 0, stream>>>(w2l[1], 100, 100, 2, bt2 + 32768);
  prep_bt<<<128, 256, 0, stream>>>(w2l[2], 100, 100, 2, bt2 + 65536);
  prep_bt<<<64,  256, 0, stream>>>(w3l[0], 100, 32,  1,  bt31);
  prep_bt<<<832, 256, 0, stream>>>(w3l[1], 100, 832, 13, bt32);
  prep_bt<<<768, 256, 0, stream>>>(w3l[2], 100, 768, 12, bt33);

  constexpr int NBLK = EDGES / 64;   // 2500

  layer_fused<1, 0, 16, 8, 8><<<NBLK, 256, 0, stream>>>(
      radii, nbr, charges, nullptr, nullptr,
      w1l[0], b1l[0], bt2, b2l[0], bt31, f0a, f1a);

  layer_fused<16, 8, 16, 8, 8><<<NBLK, 256, 0, stream>>>(
      radii, nbr, charges, f0a, f1a,
      w1l[1], b1l[1], bt2 + 32768, b2l[1], bt32, f0b, f1b);

  layer_fused<16, 8, 32, 0, 0><<<NBLK, 256, 0, stream>>>(
      radii, nbr, charges, f0b, f1b,
      w1l[2], b1l[2], bt2 + 65536, b2l[2], bt33, f0c, nullptr);

  reduce_kernel<<<32, 256, 0, stream>>>(f0c, (float*)d_out);
}